// Round 10
// baseline (513.658 us; speedup 1.0000x reference)
//
#include <hip/hip_runtime.h>
#include <math.h>

#define NN 50000
#define EE 800000
#define EP 850000   // EE + NN self loops
#define DD 128
#define NEG_SLOPE 0.2f

typedef float f4  __attribute__((ext_vector_type(4)));
typedef float f32x4 __attribute__((ext_vector_type(4)));
typedef short bf16x8 __attribute__((ext_vector_type(8)));
typedef short s4 __attribute__((ext_vector_type(4)));

// bf16 round-to-nearest-even, header-version-proof
static __device__ inline short f2bf(float f) {
    unsigned u = __float_as_uint(f);
    unsigned r = (u + 0x7FFFu + ((u >> 16) & 1u)) >> 16;
    return (short)r;
}
static __device__ inline float bf2f(short s) {
    return __uint_as_float(((unsigned)(unsigned short)s) << 16);
}

// ---------------------------------------------------------------- histogram + per-edge rank
__global__ void k_hist(const int* __restrict__ ei, int* __restrict__ counts,
                       int* __restrict__ rank) {
    int e = blockIdx.x * blockDim.x + threadIdx.x;
    if (e >= EP) return;
    int dst = (e < EE) ? ei[EE + e] : (e - EE);
    rank[e] = atomicAdd(&counts[dst], 1);
}

// ---------------------------------------------------------------- block scan (wave-shfl based)
__global__ void k_scan1(const int* __restrict__ counts, int* __restrict__ row_ptr,
                        int* __restrict__ blockSums) {
    __shared__ int wsum[16];
    int t = threadIdx.x;
    int lane = t & 63;
    int wave = t >> 6;            // 0..15
    int g = blockIdx.x * 1024 + t;
    int v = (g < NN) ? counts[g] : 0;

    int s = v;                    // inclusive scan within wave
#pragma unroll
    for (int o = 1; o < 64; o <<= 1) {
        int u = __shfl_up(s, o, 64);
        if (lane >= o) s += u;
    }
    if (lane == 63) wsum[wave] = s;
    __syncthreads();
    if (wave == 0) {
        int ws = (lane < 16) ? wsum[lane] : 0;
#pragma unroll
        for (int o = 1; o < 16; o <<= 1) {
            int u = __shfl_up(ws, o, 64);
            if (lane >= o) ws += u;
        }
        if (lane < 16) wsum[lane] = ws;
    }
    __syncthreads();
    int base = (wave > 0) ? wsum[wave - 1] : 0;
    int incl = base + s;
    if (g < NN) row_ptr[g] = incl - v;   // exclusive
    if (t == 1023) blockSums[blockIdx.x] = incl;
}

__global__ void k_scan2(const int* __restrict__ blockSums, int* __restrict__ blockOffs,
                        int nb, int* __restrict__ row_ptr) {
    if (threadIdx.x == 0 && blockIdx.x == 0) {
        int run = 0;
        for (int i = 0; i < nb; ++i) { blockOffs[i] = run; run += blockSums[i]; }
        row_ptr[NN] = run;   // == EP
    }
}

__global__ void k_scan3(int* __restrict__ row_ptr, const int* __restrict__ blockOffs) {
    int g = blockIdx.x * 1024 + threadIdx.x;
    if (g < NN) row_ptr[g] += blockOffs[blockIdx.x];
}

// ---------------------------------------------------------------- scatter into CSR (no atomics)
__global__ void k_scatter(const int* __restrict__ ei, const float* __restrict__ eattr,
                          const int* __restrict__ row_ptr, const int* __restrict__ rank,
                          int* __restrict__ src_sorted, float* __restrict__ ew_sorted) {
    int e = blockIdx.x * blockDim.x + threadIdx.x;
    if (e >= EP) return;
    int s, d; float w;
    if (e < EE) {
        s = ei[e]; d = ei[EE + e];
        float a = eattr[e];
        w = (a == 0.0f) ? 10000.0f : (1.0f / a);
    } else {
        s = d = e - EE;
        w = 0.0f;
    }
    int pos = row_ptr[d] + rank[e];
    src_sorted[pos] = s;
    ew_sorted[pos] = w;
}

// ---------------------------------------------------------------- W pre-pack (hi/lo bf16, MFMA B-fragment order)
// B-frag layout for mfma_f32_16x16x32_bf16: lane l holds col = l&15,
// k = (l>>4)*8 + j (j=0..7, contiguous 16B per lane).
__global__ void k_wpack(const float* __restrict__ W0, const float* __restrict__ W1,
                        const float* __restrict__ W2, const float* __restrict__ W3,
                        const float* __restrict__ W4, const float* __restrict__ W5,
                        short* __restrict__ dst) {
    int mat = blockIdx.x >> 6;                       // 0..5 (uniform per block)
    int e = ((blockIdx.x & 63) << 8) + threadIdx.x;  // 0..16383
    const float* W = (mat == 0) ? W0 : (mat == 1) ? W1 : (mat == 2) ? W2
                   : (mat == 3) ? W3 : (mat == 4) ? W4 : W5;
    int k = e >> 7, c = e & 127;
    float w = W[e];                                  // W[k*128 + c]
    short hb = f2bf(w);
    short lb = f2bf(w - bf2f(hb));
    int ks = k >> 5, kk = k & 31, g = kk >> 3, j = kk & 7, ct = c >> 4, cl = c & 15;
    int off = ((ks * 8 + ct) * 64 + (g * 16 + cl)) * 8 + j;
    int base = (mat >> 1) * 65536 + (mat & 1) * 32768;   // layer base + Wl/Wr
    dst[base + off] = hb;
    dst[base + 16384 + off] = lb;
}

// ---------------------------------------------------------------- MFMA dual GEMM: xl = X@Wl, xr = X@Wr
// fp32 via bf16 hi/lo split: x*w = xh*wh + xh*wl + xl*wh (lo*lo dropped, ~2^-18 rel).
// Block 64 rows x 128 cols, 4 waves each 64x32 cols (both mats). 782 blocks
// (3+ blocks/CU; round-9 lesson: 128-row tiles left half the CUs idle on the
// tail). X staged in LDS as swizzled hi/lo bf16; W from pre-packed frags.
#define GB_ROWS 64
__global__ __launch_bounds__(256, 3) void k_gemm_mfma(const float* __restrict__ X,
        const short* __restrict__ Wpk,   // this layer: [Wl-hi|Wl-lo|Wr-hi|Wr-lo] x 16384
        float* __restrict__ xl, float* __restrict__ xr, int nrows) {
    __shared__ short xh[64 * 128];       // 16 KB
    __shared__ short xlo[64 * 128];      // 16 KB
    int t = threadIdx.x;
    int rowbase = blockIdx.x * GB_ROWS;

    // stage + hi/lo convert: 64 rows x 32 f4 = 2048 f4, 8 per thread
#pragma unroll
    for (int i = 0; i < 8; ++i) {
        int idx = t + i * 256;
        int r = idx >> 5;            // 0..63
        int k4 = idx & 31;           // f4 index along k
        f4 v = {0.f, 0.f, 0.f, 0.f};
        int gr = rowbase + r;
        if (gr < nrows) v = *(const f4*)&X[gr * DD + k4 * 4];
        s4 h, l;
#pragma unroll
        for (int j = 0; j < 4; ++j) {
            short hb = f2bf(v[j]);
            h[j] = hb;
            l[j] = f2bf(v[j] - bf2f(hb));
        }
        // swizzle: 16B slot s = k4>>1 -> s ^ (r&7); 8B half = k4&1
        int si = r * 128 + (((k4 >> 1) ^ (r & 7)) << 3) + (k4 & 1) * 4;
        *(s4*)&xh[si] = h;
        *(s4*)&xlo[si] = l;
    }
    __syncthreads();

    int wave = t >> 6, lane = t & 63;

    f32x4 acc[4][2][2];
#pragma unroll
    for (int rt = 0; rt < 4; ++rt)
#pragma unroll
        for (int ct = 0; ct < 2; ++ct) {
            acc[rt][ct][0] = (f32x4){0.f, 0.f, 0.f, 0.f};
            acc[rt][ct][1] = (f32x4){0.f, 0.f, 0.f, 0.f};
        }

    for (int ks = 0; ks < 4; ++ks) {
        bf16x8 Ah[4], Al[4];
#pragma unroll
        for (int rt = 0; rt < 4; ++rt) {
            int row = rt * 16 + (lane & 15);
            int slot = ks * 4 + (lane >> 4);
            int si = row * 128 + ((slot ^ (row & 7)) << 3);
            Ah[rt] = *(const bf16x8*)&xh[si];
            Al[rt] = *(const bf16x8*)&xlo[si];
        }
#pragma unroll
        for (int ct = 0; ct < 2; ++ct) {
            int ctg = wave * 2 + ct;
            int fb = ((ks * 8 + ctg) * 64 + lane) * 8;
            bf16x8 Blh = *(const bf16x8*)&Wpk[fb];
            bf16x8 Bll = *(const bf16x8*)&Wpk[16384 + fb];
            bf16x8 Brh = *(const bf16x8*)&Wpk[32768 + fb];
            bf16x8 Brl = *(const bf16x8*)&Wpk[49152 + fb];
#pragma unroll
            for (int rt = 0; rt < 4; ++rt) {
                acc[rt][ct][0] = __builtin_amdgcn_mfma_f32_16x16x32_bf16(Ah[rt], Blh, acc[rt][ct][0], 0, 0, 0);
                acc[rt][ct][0] = __builtin_amdgcn_mfma_f32_16x16x32_bf16(Ah[rt], Bll, acc[rt][ct][0], 0, 0, 0);
                acc[rt][ct][0] = __builtin_amdgcn_mfma_f32_16x16x32_bf16(Al[rt], Blh, acc[rt][ct][0], 0, 0, 0);
                acc[rt][ct][1] = __builtin_amdgcn_mfma_f32_16x16x32_bf16(Ah[rt], Brh, acc[rt][ct][1], 0, 0, 0);
                acc[rt][ct][1] = __builtin_amdgcn_mfma_f32_16x16x32_bf16(Ah[rt], Brl, acc[rt][ct][1], 0, 0, 0);
                acc[rt][ct][1] = __builtin_amdgcn_mfma_f32_16x16x32_bf16(Al[rt], Brh, acc[rt][ct][1], 0, 0, 0);
            }
        }
    }

    // epilogue: D layout col = lane&15, row = (lane>>4)*4 + reg
#pragma unroll
    for (int rt = 0; rt < 4; ++rt) {
#pragma unroll
        for (int reg = 0; reg < 4; ++reg) {
            int row = rowbase + rt * 16 + (lane >> 4) * 4 + reg;
            if (row < nrows) {
#pragma unroll
                for (int ct = 0; ct < 2; ++ct) {
                    int col = wave * 32 + ct * 16 + (lane & 15);
                    xl[row * DD + col] = acc[rt][ct][0][reg];
                    xr[row * DD + col] = acc[rt][ct][1][reg];
                }
            }
        }
    }
}

// ---------------------------------------------------------------- aggregation
// Wave per node; each 8-lane GROUP owns its own edge stream (8 edges in
// flight per wave), lane covers 16 channels (4x f4). Online softmax per
// group, merged pairwise at the end (3 levels). Next iteration prefetched
// before the current compute. FUSE_FINAL: layer 3 dots with Wlin directly.
__device__ inline f4 lrelu4(f4 v) {
    f4 r;
    r.x = v.x > 0.f ? v.x : NEG_SLOPE * v.x;
    r.y = v.y > 0.f ? v.y : NEG_SLOPE * v.y;
    r.z = v.z > 0.f ? v.z : NEG_SLOPE * v.z;
    r.w = v.w > 0.f ? v.w : NEG_SLOPE * v.w;
    return r;
}
__device__ inline float dot4(f4 a, f4 b) {
    return a.x * b.x + a.y * b.y + a.z * b.z + a.w * b.w;
}

template<bool DO_RELU, bool FUSE_FINAL>
__global__ __launch_bounds__(256) void k_agg_t(const float* __restrict__ xl,
        const float* __restrict__ xr, const int* __restrict__ row_ptr,
        const int* __restrict__ src_sorted, const float* __restrict__ ew_sorted,
        const float* __restrict__ We, const float* __restrict__ att,
        const float* __restrict__ bias, float* __restrict__ out,
        const float* __restrict__ Wlin, const float* __restrict__ blin,
        float* __restrict__ outS) {
    int wid = (blockIdx.x * blockDim.x + threadIdx.x) >> 6;
    int lane = threadIdx.x & 63;
    if (wid >= NN) return;
    int grp = lane >> 3;           // 0..7
    int c = (lane & 7) * 16;       // 16 channels per lane

    f4 xrv[4], attv[4], Wev[4];
#pragma unroll
    for (int j = 0; j < 4; ++j) {
        xrv[j]  = *(const f4*)&xr[wid * DD + c + 4 * j];
        attv[j] = *(const f4*)&att[c + 4 * j];
        Wev[j]  = *(const f4*)&We[c + 4 * j];
    }

    int beg = row_ptr[wid];
    int end = row_ptr[wid + 1];
    int niter = (end - beg + 7) >> 3;

    float m = -1e30f;     // finite "minus infinity": keeps exp() NaN-free
    float d = 0.0f;
    f4 acc[4];
#pragma unroll
    for (int j = 0; j < 4; ++j) acc[j] = (f4){0.f, 0.f, 0.f, 0.f};

    // prologue: load iteration 0's edge data
    int e0 = beg + grp;
    bool val_cur = (e0 < end);
    int ee0 = val_cur ? e0 : (end - 1);
    float w_cur = ew_sorted[ee0];
    int s_cur = src_sorted[ee0];
    f4 xc[4];
#pragma unroll
    for (int j = 0; j < 4; ++j) xc[j] = *(const f4*)&xl[s_cur * DD + c + 4 * j];

    for (int i = 0; i < niter; ++i) {
        // prefetch iteration i+1 (independent of the softmax chain)
        f4 xn[4];
#pragma unroll
        for (int j = 0; j < 4; ++j) xn[j] = (f4){0.f, 0.f, 0.f, 0.f};
        float w_nxt = 0.f; bool val_nxt = false;
        if (i + 1 < niter) {
            int e = beg + 8 * (i + 1) + grp;
            val_nxt = (e < end);
            int ee = val_nxt ? e : (end - 1);
            w_nxt = ew_sorted[ee];
            int sn = src_sorted[ee];
#pragma unroll
            for (int j = 0; j < 4; ++j) xn[j] = *(const f4*)&xl[sn * DD + c + 4 * j];
        }

        float p = 0.f;
#pragma unroll
        for (int j = 0; j < 4; ++j)
            p += dot4(lrelu4(xc[j] + xrv[j] + w_cur * Wev[j]), attv[j]);
#pragma unroll
        for (int o = 4; o >= 1; o >>= 1) p += __shfl_xor(p, o, 64);   // within 8-lane group

        float logit = val_cur ? p : -1e30f;
        float nm = fmaxf(m, logit);
        float sc = __expf(m - nm);
        float pe = __expf(logit - nm);
        d = d * sc + pe;
#pragma unroll
        for (int j = 0; j < 4; ++j) acc[j] = acc[j] * sc + pe * xc[j];
        m = nm;

#pragma unroll
        for (int j = 0; j < 4; ++j) xc[j] = xn[j];
        w_cur = w_nxt; val_cur = val_nxt;
    }

    // merge the 8 group states (lanes l, l+8, l+16, ... hold same channels)
#pragma unroll
    for (int o = 8; o <= 32; o <<= 1) {
        float mo = __shfl_xor(m, o, 64);
        float dn = __shfl_xor(d, o, 64);
        f4 ao[4];
#pragma unroll
        for (int j = 0; j < 4; ++j) {
            ao[j].x = __shfl_xor(acc[j].x, o, 64);
            ao[j].y = __shfl_xor(acc[j].y, o, 64);
            ao[j].z = __shfl_xor(acc[j].z, o, 64);
            ao[j].w = __shfl_xor(acc[j].w, o, 64);
        }
        float M  = fmaxf(m, mo);
        float sA = __expf(m - M);
        float sB = __expf(mo - M);
        d = d * sA + dn * sB;
#pragma unroll
        for (int j = 0; j < 4; ++j) acc[j] = acc[j] * sA + ao[j] * sB;
        m = M;
    }

    if (grp == 0) {
        float inv = 1.0f / d;
        f4 o[4];
#pragma unroll
        for (int j = 0; j < 4; ++j) {
            f4 bv = *(const f4*)&bias[c + 4 * j];
            o[j] = acc[j] * inv + bv;
            if (DO_RELU) {
                o[j].x = fmaxf(o[j].x, 0.f); o[j].y = fmaxf(o[j].y, 0.f);
                o[j].z = fmaxf(o[j].z, 0.f); o[j].w = fmaxf(o[j].w, 0.f);
            }
        }
        if (FUSE_FINAL) {
            // out[wid] = h[wid] . Wlin + blin, h never materialized
            float p = 0.f;
#pragma unroll
            for (int j = 0; j < 4; ++j)
                p += dot4(o[j], *(const f4*)&Wlin[c + 4 * j]);
#pragma unroll
            for (int oo = 4; oo >= 1; oo >>= 1) p += __shfl_xor(p, oo, 64);
            if (lane == 0) outS[wid] = p + blin[0];
        } else {
#pragma unroll
            for (int j = 0; j < 4; ++j)
                *(f4*)&out[wid * DD + c + 4 * j] = o[j];
        }
    }
}

// ----------------------------------------------------------------
static inline size_t align256(size_t x) { return (x + 255) & ~(size_t)255; }

extern "C" void kernel_launch(void* const* d_in, const int* in_sizes, int n_in,
                              void* d_out, int out_size, void* d_ws, size_t ws_size,
                              hipStream_t stream) {
    const float* x     = (const float*)d_in[0];
    const int*   ei    = (const int*)d_in[1];
    const float* eattr = (const float*)d_in[2];
    const float* Wl[3]  = {(const float*)d_in[3],  (const float*)d_in[8],  (const float*)d_in[13]};
    const float* Wr[3]  = {(const float*)d_in[4],  (const float*)d_in[9],  (const float*)d_in[14]};
    const float* We[3]  = {(const float*)d_in[5],  (const float*)d_in[10], (const float*)d_in[15]};
    const float* att[3] = {(const float*)d_in[6],  (const float*)d_in[11], (const float*)d_in[16]};
    const float* bb[3]  = {(const float*)d_in[7],  (const float*)d_in[12], (const float*)d_in[17]};
    const float* Wlin = (const float*)d_in[18];
    const float* blin = (const float*)d_in[19];

    char* p = (char*)d_ws;
    int* counts = (int*)p;          p += align256((size_t)NN * 4);
    int* rank   = (int*)p;          p += align256((size_t)EP * 4);
    int* row_ptr= (int*)p;          p += align256((size_t)(NN + 1) * 4);
    int* blockSums = (int*)p;       p += align256(64 * 4);
    int* blockOffs = (int*)p;       p += align256(64 * 4);
    int* src_sorted = (int*)p;      p += align256((size_t)EP * 4);
    float* ew_sorted = (float*)p;   p += align256((size_t)EP * 4);
    float* xl = (float*)p;          p += align256((size_t)NN * DD * 4);
    float* xr = (float*)p;          p += align256((size_t)NN * DD * 4);
    float* hA = (float*)p;          p += align256((size_t)NN * DD * 4);
    float* hB = (float*)p;          p += align256((size_t)NN * DD * 4);
    short* wpk = (short*)p;         p += align256((size_t)3 * 65536 * 2);  // 384 KB

    hipMemsetAsync(counts, 0, (size_t)NN * 4, stream);

    const int nb_scan = (NN + 1023) / 1024;   // 49
    k_hist<<<(EP + 255) / 256, 256, 0, stream>>>(ei, counts, rank);
    k_scan1<<<nb_scan, 1024, 0, stream>>>(counts, row_ptr, blockSums);
    k_scan2<<<1, 64, 0, stream>>>(blockSums, blockOffs, nb_scan, row_ptr);
    k_scan3<<<nb_scan, 1024, 0, stream>>>(row_ptr, blockOffs);
    k_scatter<<<(EP + 255) / 256, 256, 0, stream>>>(ei, eattr, row_ptr, rank, src_sorted, ew_sorted);

    // pre-pack all 6 weight matrices into hi/lo bf16 MFMA fragments
    k_wpack<<<6 * 64, 256, 0, stream>>>(Wl[0], Wr[0], Wl[1], Wr[1], Wl[2], Wr[2], wpk);

    const int gemm_grid = (NN + GB_ROWS - 1) / GB_ROWS;   // 782
    const int agg_grid  = (NN + 3) / 4;                   // 4 waves per block

    // layer 1: x -> hA (relu)
    k_gemm_mfma<<<gemm_grid, 256, 0, stream>>>(x, wpk + 0 * 65536, xl, xr, NN);
    k_agg_t<true, false><<<agg_grid, 256, 0, stream>>>(xl, xr, row_ptr, src_sorted, ew_sorted,
                                        We[0], att[0], bb[0], hA, nullptr, nullptr, nullptr);
    // layer 2: hA -> hB (relu)
    k_gemm_mfma<<<gemm_grid, 256, 0, stream>>>(hA, wpk + 1 * 65536, xl, xr, NN);
    k_agg_t<true, false><<<agg_grid, 256, 0, stream>>>(xl, xr, row_ptr, src_sorted, ew_sorted,
                                        We[1], att[1], bb[1], hB, nullptr, nullptr, nullptr);
    // layer 3: hB -> (fused final linear) -> d_out
    k_gemm_mfma<<<gemm_grid, 256, 0, stream>>>(hB, wpk + 2 * 65536, xl, xr, NN);
    k_agg_t<false, true><<<agg_grid, 256, 0, stream>>>(xl, xr, row_ptr, src_sorted, ew_sorted,
                                        We[2], att[2], bb[2], nullptr, Wlin, blin, (float*)d_out);
}

// Round 12
// 447.388 us; speedup vs baseline: 1.1481x; 1.1481x over previous
//
#include <hip/hip_runtime.h>
#include <math.h>

#define NN 50000
#define EE 800000
#define EP 850000   // EE + NN self loops
#define DD 128
#define NEG_SLOPE 0.2f

typedef float f4  __attribute__((ext_vector_type(4)));
typedef float f32x4 __attribute__((ext_vector_type(4)));
typedef short bf16x8 __attribute__((ext_vector_type(8)));
typedef short s4 __attribute__((ext_vector_type(4)));

// bf16 round-to-nearest-even, header-version-proof
static __device__ inline short f2bf(float f) {
    unsigned u = __float_as_uint(f);
    unsigned r = (u + 0x7FFFu + ((u >> 16) & 1u)) >> 16;
    return (short)r;
}
static __device__ inline float bf2f(short s) {
    return __uint_as_float(((unsigned)(unsigned short)s) << 16);
}

// ---------------------------------------------------------------- histogram + per-edge rank
__global__ void k_hist(const int* __restrict__ ei, int* __restrict__ counts,
                       int* __restrict__ rank) {
    int e = blockIdx.x * blockDim.x + threadIdx.x;
    if (e >= EP) return;
    int dst = (e < EE) ? ei[EE + e] : (e - EE);
    rank[e] = atomicAdd(&counts[dst], 1);
}

// ---------------------------------------------------------------- block scan (wave-shfl based)
__global__ void k_scan1(const int* __restrict__ counts, int* __restrict__ row_ptr,
                        int* __restrict__ blockSums) {
    __shared__ int wsum[16];
    int t = threadIdx.x;
    int lane = t & 63;
    int wave = t >> 6;            // 0..15
    int g = blockIdx.x * 1024 + t;
    int v = (g < NN) ? counts[g] : 0;

    int s = v;                    // inclusive scan within wave
#pragma unroll
    for (int o = 1; o < 64; o <<= 1) {
        int u = __shfl_up(s, o, 64);
        if (lane >= o) s += u;
    }
    if (lane == 63) wsum[wave] = s;
    __syncthreads();
    if (wave == 0) {
        int ws = (lane < 16) ? wsum[lane] : 0;
#pragma unroll
        for (int o = 1; o < 16; o <<= 1) {
            int u = __shfl_up(ws, o, 64);
            if (lane >= o) ws += u;
        }
        if (lane < 16) wsum[lane] = ws;
    }
    __syncthreads();
    int base = (wave > 0) ? wsum[wave - 1] : 0;
    int incl = base + s;
    if (g < NN) row_ptr[g] = incl - v;   // exclusive
    if (t == 1023) blockSums[blockIdx.x] = incl;
}

__global__ void k_scan2(const int* __restrict__ blockSums, int* __restrict__ blockOffs,
                        int nb, int* __restrict__ row_ptr) {
    if (threadIdx.x == 0 && blockIdx.x == 0) {
        int run = 0;
        for (int i = 0; i < nb; ++i) { blockOffs[i] = run; run += blockSums[i]; }
        row_ptr[NN] = run;   // == EP
    }
}

__global__ void k_scan3(int* __restrict__ row_ptr, const int* __restrict__ blockOffs) {
    int g = blockIdx.x * 1024 + threadIdx.x;
    if (g < NN) row_ptr[g] += blockOffs[blockIdx.x];
}

// ---------------------------------------------------------------- scatter into CSR (no atomics)
__global__ void k_scatter(const int* __restrict__ ei, const float* __restrict__ eattr,
                          const int* __restrict__ row_ptr, const int* __restrict__ rank,
                          int* __restrict__ src_sorted, float* __restrict__ ew_sorted) {
    int e = blockIdx.x * blockDim.x + threadIdx.x;
    if (e >= EP) return;
    int s, d; float w;
    if (e < EE) {
        s = ei[e]; d = ei[EE + e];
        float a = eattr[e];
        w = (a == 0.0f) ? 10000.0f : (1.0f / a);
    } else {
        s = d = e - EE;
        w = 0.0f;
    }
    int pos = row_ptr[d] + rank[e];
    src_sorted[pos] = s;
    ew_sorted[pos] = w;
}

// ---------------------------------------------------------------- W pre-pack (hi/lo bf16, MFMA B-fragment order)
// B-frag layout for mfma_f32_16x16x32_bf16: lane l holds col = l&15,
// k = (l>>4)*8 + j (j=0..7, contiguous 16B per lane).
__global__ void k_wpack(const float* __restrict__ W0, const float* __restrict__ W1,
                        const float* __restrict__ W2, const float* __restrict__ W3,
                        const float* __restrict__ W4, const float* __restrict__ W5,
                        short* __restrict__ dst) {
    int mat = blockIdx.x >> 6;                       // 0..5 (uniform per block)
    int e = ((blockIdx.x & 63) << 8) + threadIdx.x;  // 0..16383
    const float* W = (mat == 0) ? W0 : (mat == 1) ? W1 : (mat == 2) ? W2
                   : (mat == 3) ? W3 : (mat == 4) ? W4 : W5;
    int k = e >> 7, c = e & 127;
    float w = W[e];                                  // W[k*128 + c]
    short hb = f2bf(w);
    short lb = f2bf(w - bf2f(hb));
    int ks = k >> 5, kk = k & 31, g = kk >> 3, j = kk & 7, ct = c >> 4, cl = c & 15;
    int off = ((ks * 8 + ct) * 64 + (g * 16 + cl)) * 8 + j;
    int base = (mat >> 1) * 65536 + (mat & 1) * 32768;   // layer base + Wl/Wr
    dst[base + off] = hb;
    dst[base + 16384 + off] = lb;
}

// ---------------------------------------------------------------- MFMA dual GEMM: xl = X@Wl, xr = X@Wr
// fp32 via bf16 hi/lo split: x*w = xh*wh + xh*wl + xl*wh (lo*lo dropped, ~2^-18 rel).
// Block 64 rows x 128 cols, 4 waves each 64x32 cols (both mats). 782 blocks
// (3+ blocks/CU). X staged in LDS as swizzled hi/lo bf16; W from pre-packed frags.
#define GB_ROWS 64
__global__ __launch_bounds__(256, 3) void k_gemm_mfma(const float* __restrict__ X,
        const short* __restrict__ Wpk,   // this layer: [Wl-hi|Wl-lo|Wr-hi|Wr-lo] x 16384
        float* __restrict__ xl, float* __restrict__ xr, int nrows) {
    __shared__ short xh[64 * 128];       // 16 KB
    __shared__ short xlo[64 * 128];      // 16 KB
    int t = threadIdx.x;
    int rowbase = blockIdx.x * GB_ROWS;

    // stage + hi/lo convert: 64 rows x 32 f4 = 2048 f4, 8 per thread
#pragma unroll
    for (int i = 0; i < 8; ++i) {
        int idx = t + i * 256;
        int r = idx >> 5;            // 0..63
        int k4 = idx & 31;           // f4 index along k
        f4 v = {0.f, 0.f, 0.f, 0.f};
        int gr = rowbase + r;
        if (gr < nrows) v = *(const f4*)&X[gr * DD + k4 * 4];
        s4 h, l;
#pragma unroll
        for (int j = 0; j < 4; ++j) {
            short hb = f2bf(v[j]);
            h[j] = hb;
            l[j] = f2bf(v[j] - bf2f(hb));
        }
        // swizzle: 16B slot s = k4>>1 -> s ^ (r&7); 8B half = k4&1
        int si = r * 128 + (((k4 >> 1) ^ (r & 7)) << 3) + (k4 & 1) * 4;
        *(s4*)&xh[si] = h;
        *(s4*)&xlo[si] = l;
    }
    __syncthreads();

    int wave = t >> 6, lane = t & 63;

    f32x4 acc[4][2][2];
#pragma unroll
    for (int rt = 0; rt < 4; ++rt)
#pragma unroll
        for (int ct = 0; ct < 2; ++ct) {
            acc[rt][ct][0] = (f32x4){0.f, 0.f, 0.f, 0.f};
            acc[rt][ct][1] = (f32x4){0.f, 0.f, 0.f, 0.f};
        }

    for (int ks = 0; ks < 4; ++ks) {
        bf16x8 Ah[4], Al[4];
#pragma unroll
        for (int rt = 0; rt < 4; ++rt) {
            int row = rt * 16 + (lane & 15);
            int slot = ks * 4 + (lane >> 4);
            int si = row * 128 + ((slot ^ (row & 7)) << 3);
            Ah[rt] = *(const bf16x8*)&xh[si];
            Al[rt] = *(const bf16x8*)&xlo[si];
        }
#pragma unroll
        for (int ct = 0; ct < 2; ++ct) {
            int ctg = wave * 2 + ct;
            int fb = ((ks * 8 + ctg) * 64 + lane) * 8;
            bf16x8 Blh = *(const bf16x8*)&Wpk[fb];
            bf16x8 Bll = *(const bf16x8*)&Wpk[16384 + fb];
            bf16x8 Brh = *(const bf16x8*)&Wpk[32768 + fb];
            bf16x8 Brl = *(const bf16x8*)&Wpk[49152 + fb];
#pragma unroll
            for (int rt = 0; rt < 4; ++rt) {
                acc[rt][ct][0] = __builtin_amdgcn_mfma_f32_16x16x32_bf16(Ah[rt], Blh, acc[rt][ct][0], 0, 0, 0);
                acc[rt][ct][0] = __builtin_amdgcn_mfma_f32_16x16x32_bf16(Ah[rt], Bll, acc[rt][ct][0], 0, 0, 0);
                acc[rt][ct][0] = __builtin_amdgcn_mfma_f32_16x16x32_bf16(Al[rt], Blh, acc[rt][ct][0], 0, 0, 0);
                acc[rt][ct][1] = __builtin_amdgcn_mfma_f32_16x16x32_bf16(Ah[rt], Brh, acc[rt][ct][1], 0, 0, 0);
                acc[rt][ct][1] = __builtin_amdgcn_mfma_f32_16x16x32_bf16(Ah[rt], Brl, acc[rt][ct][1], 0, 0, 0);
                acc[rt][ct][1] = __builtin_amdgcn_mfma_f32_16x16x32_bf16(Al[rt], Brh, acc[rt][ct][1], 0, 0, 0);
            }
        }
    }

    // epilogue: D layout col = lane&15, row = (lane>>4)*4 + reg
#pragma unroll
    for (int rt = 0; rt < 4; ++rt) {
#pragma unroll
        for (int reg = 0; reg < 4; ++reg) {
            int row = rowbase + rt * 16 + (lane >> 4) * 4 + reg;
            if (row < nrows) {
#pragma unroll
                for (int ct = 0; ct < 2; ++ct) {
                    int col = wave * 32 + ct * 16 + (lane & 15);
                    xl[row * DD + col] = acc[rt][ct][0][reg];
                    xr[row * DD + col] = acc[rt][ct][1][reg];
                }
            }
        }
    }
}

// ---------------------------------------------------------------- aggregation
// Wave per node; each 16-lane QUARTER owns its own edge stream (4 edges in
// flight per wave), lane covers 8 channels. Online softmax per quarter,
// merged pairwise at the end. Next iteration's (index, weight, gather) is
// prefetched before the current compute to hide the dependent load chain.
// (round-10 lesson: 8 streams/wave costs VGPR occupancy + tail waste; 4 is
// the sweet spot — measured 73 vs 101 us.)
// FUSE_FINAL: layer 3 skips writing h and directly dots with Wlin.
__device__ inline f4 lrelu4(f4 v) {
    f4 r;
    r.x = v.x > 0.f ? v.x : NEG_SLOPE * v.x;
    r.y = v.y > 0.f ? v.y : NEG_SLOPE * v.y;
    r.z = v.z > 0.f ? v.z : NEG_SLOPE * v.z;
    r.w = v.w > 0.f ? v.w : NEG_SLOPE * v.w;
    return r;
}

template<bool DO_RELU, bool FUSE_FINAL>
__global__ __launch_bounds__(256) void k_agg_t(const float* __restrict__ xl,
        const float* __restrict__ xr, const int* __restrict__ row_ptr,
        const int* __restrict__ src_sorted, const float* __restrict__ ew_sorted,
        const float* __restrict__ We, const float* __restrict__ att,
        const float* __restrict__ bias, float* __restrict__ out,
        const float* __restrict__ Wlin, const float* __restrict__ blin,
        float* __restrict__ outS) {
    int wid = (blockIdx.x * blockDim.x + threadIdx.x) >> 6;
    int lane = threadIdx.x & 63;
    if (wid >= NN) return;
    int quarter = lane >> 4;       // 0..3
    int c = (lane & 15) * 8;       // 8 channels per lane

    const f4 xrv0 = *(const f4*)&xr[wid * DD + c];
    const f4 xrv1 = *(const f4*)&xr[wid * DD + c + 4];
    const f4 att0 = *(const f4*)&att[c];
    const f4 att1 = *(const f4*)&att[c + 4];
    const f4 We0  = *(const f4*)&We[c];
    const f4 We1  = *(const f4*)&We[c + 4];

    int beg = row_ptr[wid];
    int end = row_ptr[wid + 1];
    int niter = (end - beg + 3) >> 2;

    float m = -1e30f;     // finite "minus infinity": keeps exp() NaN-free
    float d = 0.0f;
    f4 acc0 = {0,0,0,0}, acc1 = {0,0,0,0};

    // prologue: load iteration 0's edge data
    int e0 = beg + quarter;
    bool val_cur = (e0 < end);
    int ee0 = val_cur ? e0 : (end - 1);
    float w_cur = ew_sorted[ee0];
    int s_cur = src_sorted[ee0];
    f4 x0c = *(const f4*)&xl[s_cur * DD + c];
    f4 x1c = *(const f4*)&xl[s_cur * DD + c + 4];

    for (int i = 0; i < niter; ++i) {
        // prefetch iteration i+1 (independent of the softmax chain)
        f4 x0n = {0,0,0,0}, x1n = {0,0,0,0};
        float w_nxt = 0.f; bool val_nxt = false;
        if (i + 1 < niter) {
            int e = beg + 4 * (i + 1) + quarter;
            val_nxt = (e < end);
            int ee = val_nxt ? e : (end - 1);
            w_nxt = ew_sorted[ee];
            int sn = src_sorted[ee];
            x0n = *(const f4*)&xl[sn * DD + c];
            x1n = *(const f4*)&xl[sn * DD + c + 4];
        }

        f4 t0 = lrelu4(x0c + xrv0 + w_cur * We0);
        f4 t1 = lrelu4(x1c + xrv1 + w_cur * We1);
        float p = t0.x * att0.x + t0.y * att0.y + t0.z * att0.z + t0.w * att0.w
                + t1.x * att1.x + t1.y * att1.y + t1.z * att1.z + t1.w * att1.w;
#pragma unroll
        for (int o = 8; o >= 1; o >>= 1) p += __shfl_xor(p, o, 64);   // within quarter

        float logit = val_cur ? p : -1e30f;
        float nm = fmaxf(m, logit);
        float sc = __expf(m - nm);
        float pe = __expf(logit - nm);
        d = d * sc + pe;
        acc0 = acc0 * sc + pe * x0c;
        acc1 = acc1 * sc + pe * x1c;
        m = nm;

        x0c = x0n; x1c = x1n; w_cur = w_nxt; val_cur = val_nxt;
    }

    // merge the 4 quarter states (lanes l, l+16, l+32, l+48 hold same channels)
#pragma unroll
    for (int o = 16; o <= 32; o <<= 1) {
        float mo = __shfl_xor(m, o, 64);
        float dn = __shfl_xor(d, o, 64);
        f4 a0o, a1o;
        a0o.x = __shfl_xor(acc0.x, o, 64); a0o.y = __shfl_xor(acc0.y, o, 64);
        a0o.z = __shfl_xor(acc0.z, o, 64); a0o.w = __shfl_xor(acc0.w, o, 64);
        a1o.x = __shfl_xor(acc1.x, o, 64); a1o.y = __shfl_xor(acc1.y, o, 64);
        a1o.z = __shfl_xor(acc1.z, o, 64); a1o.w = __shfl_xor(acc1.w, o, 64);
        float M  = fmaxf(m, mo);
        float sA = __expf(m - M);
        float sB = __expf(mo - M);
        d = d * sA + dn * sB;
        acc0 = acc0 * sA + a0o * sB;
        acc1 = acc1 * sA + a1o * sB;
        m = M;
    }

    if (quarter == 0) {
        float inv = 1.0f / d;
        f4 bv0 = *(const f4*)&bias[c];
        f4 bv1 = *(const f4*)&bias[c + 4];
        f4 o0 = acc0 * inv + bv0;
        f4 o1 = acc1 * inv + bv1;
        if (DO_RELU) {
            o0.x = fmaxf(o0.x, 0.f); o0.y = fmaxf(o0.y, 0.f);
            o0.z = fmaxf(o0.z, 0.f); o0.w = fmaxf(o0.w, 0.f);
            o1.x = fmaxf(o1.x, 0.f); o1.y = fmaxf(o1.y, 0.f);
            o1.z = fmaxf(o1.z, 0.f); o1.w = fmaxf(o1.w, 0.f);
        }
        if (FUSE_FINAL) {
            // out[wid] = h[wid] . Wlin + blin, h never materialized
            f4 wl0 = *(const f4*)&Wlin[c];
            f4 wl1 = *(const f4*)&Wlin[c + 4];
            float p = o0.x * wl0.x + o0.y * wl0.y + o0.z * wl0.z + o0.w * wl0.w
                    + o1.x * wl1.x + o1.y * wl1.y + o1.z * wl1.z + o1.w * wl1.w;
#pragma unroll
            for (int o = 8; o >= 1; o >>= 1) p += __shfl_xor(p, o, 64);
            if (lane == 0) outS[wid] = p + blin[0];
        } else {
            *(f4*)&out[wid * DD + c] = o0;
            *(f4*)&out[wid * DD + c + 4] = o1;
        }
    }
}

// ----------------------------------------------------------------
static inline size_t align256(size_t x) { return (x + 255) & ~(size_t)255; }

extern "C" void kernel_launch(void* const* d_in, const int* in_sizes, int n_in,
                              void* d_out, int out_size, void* d_ws, size_t ws_size,
                              hipStream_t stream) {
    const float* x     = (const float*)d_in[0];
    const int*   ei    = (const int*)d_in[1];
    const float* eattr = (const float*)d_in[2];
    const float* Wl[3]  = {(const float*)d_in[3],  (const float*)d_in[8],  (const float*)d_in[13]};
    const float* Wr[3]  = {(const float*)d_in[4],  (const float*)d_in[9],  (const float*)d_in[14]};
    const float* We[3]  = {(const float*)d_in[5],  (const float*)d_in[10], (const float*)d_in[15]};
    const float* att[3] = {(const float*)d_in[6],  (const float*)d_in[11], (const float*)d_in[16]};
    const float* bb[3]  = {(const float*)d_in[7],  (const float*)d_in[12], (const float*)d_in[17]};
    const float* Wlin = (const float*)d_in[18];
    const float* blin = (const float*)d_in[19];

    char* p = (char*)d_ws;
    int* counts = (int*)p;          p += align256((size_t)NN * 4);
    int* rank   = (int*)p;          p += align256((size_t)EP * 4);
    int* row_ptr= (int*)p;          p += align256((size_t)(NN + 1) * 4);
    int* blockSums = (int*)p;       p += align256(64 * 4);
    int* blockOffs = (int*)p;       p += align256(64 * 4);
    int* src_sorted = (int*)p;      p += align256((size_t)EP * 4);
    float* ew_sorted = (float*)p;   p += align256((size_t)EP * 4);
    float* xl = (float*)p;          p += align256((size_t)NN * DD * 4);
    float* xr = (float*)p;          p += align256((size_t)NN * DD * 4);
    float* hA = (float*)p;          p += align256((size_t)NN * DD * 4);
    float* hB = (float*)p;          p += align256((size_t)NN * DD * 4);
    short* wpk = (short*)p;         p += align256((size_t)3 * 65536 * 2);  // 384 KB

    hipMemsetAsync(counts, 0, (size_t)NN * 4, stream);

    const int nb_scan = (NN + 1023) / 1024;   // 49
    k_hist<<<(EP + 255) / 256, 256, 0, stream>>>(ei, counts, rank);
    k_scan1<<<nb_scan, 1024, 0, stream>>>(counts, row_ptr, blockSums);
    k_scan2<<<1, 64, 0, stream>>>(blockSums, blockOffs, nb_scan, row_ptr);
    k_scan3<<<nb_scan, 1024, 0, stream>>>(row_ptr, blockOffs);
    k_scatter<<<(EP + 255) / 256, 256, 0, stream>>>(ei, eattr, row_ptr, rank, src_sorted, ew_sorted);

    // pre-pack all 6 weight matrices into hi/lo bf16 MFMA fragments
    k_wpack<<<6 * 64, 256, 0, stream>>>(Wl[0], Wr[0], Wl[1], Wr[1], Wl[2], Wr[2], wpk);

    const int gemm_grid = (NN + GB_ROWS - 1) / GB_ROWS;   // 782
    const int agg_grid  = (NN + 3) / 4;                   // 4 waves per block

    // layer 1: x -> hA (relu)
    k_gemm_mfma<<<gemm_grid, 256, 0, stream>>>(x, wpk + 0 * 65536, xl, xr, NN);
    k_agg_t<true, false><<<agg_grid, 256, 0, stream>>>(xl, xr, row_ptr, src_sorted, ew_sorted,
                                        We[0], att[0], bb[0], hA, nullptr, nullptr, nullptr);
    // layer 2: hA -> hB (relu)
    k_gemm_mfma<<<gemm_grid, 256, 0, stream>>>(hA, wpk + 1 * 65536, xl, xr, NN);
    k_agg_t<true, false><<<agg_grid, 256, 0, stream>>>(xl, xr, row_ptr, src_sorted, ew_sorted,
                                        We[1], att[1], bb[1], hB, nullptr, nullptr, nullptr);
    // layer 3: hB -> (fused final linear) -> d_out
    k_gemm_mfma<<<gemm_grid, 256, 0, stream>>>(hB, wpk + 2 * 65536, xl, xr, NN);
    k_agg_t<false, true><<<agg_grid, 256, 0, stream>>>(xl, xr, row_ptr, src_sorted, ew_sorted,
                                        We[2], att[2], bb[2], nullptr, Wlin, blin, (float*)d_out);
}